// Round 12
// baseline (233.003 us; speedup 1.0000x reference)
//
#include <hip/hip_runtime.h>

typedef _Float16 f16;
typedef f16 f16x8 __attribute__((ext_vector_type(8)));
typedef f16 f16x4v __attribute__((ext_vector_type(4)));
typedef f16 f16x2v __attribute__((ext_vector_type(2)));
typedef float f32x4 __attribute__((ext_vector_type(4)));

// async global->LDS, 16B per lane. LDS dest is wave-uniform base; HW scatters
// lane i's 16B to base + i*16.
__device__ __forceinline__ void async_ld16(const void* g, void* l) {
    __builtin_amdgcn_global_load_lds(
        (const __attribute__((address_space(1))) unsigned int*)g,
        (__attribute__((address_space(3))) unsigned int*)l, 16, 0, 0);
}

#define VMC(n) asm volatile("s_waitcnt vmcnt(" #n ")" ::: "memory")
#define BAR __builtin_amdgcn_s_barrier()

// ============================================================================
// r19: qkv occupancy doubling. r18 post-mortem: sync-halving was neutral ->
// sync latency per se is not the binder. Model: 64x64 wave tile = 32 FLOP per
// LDS-read byte; CU MFMA peak (4069 FLOP/cyc) needs 127 B/cyc LDS = the
// hardware limit -> qkv is LDS-BW-bound with ~24 us of unoverlapped sync at
// 1 block/CU (LDS floor ~41 us, measured 65). Fix: 3 x 24 KiB buffers
// (72 KiB) -> 2 blocks/CU; 16 waves/CU TLP hides barrier+vmcnt stalls under
// the other block's LDS work (m114 mechanism). Same per-phase instruction
// stream as r17 (8 ds_read + 3 stage + 16 MFMA, same K-order) ->
// bit-identical outputs. Staging 1 K-step(32) ahead x2; VMC(3)/phase.
// ============================================================================

// ============================================================================
// scores128: P[b][q][k] = exp((Q.K^T)/32) f16, causal-zeroed.
// BM=BN=128, BK=64, 256 thr = 4 waves (2M x 2N), wave C = 64x64 = 4x4 frags.
// LDS = 2 buf x (A 128x64 + B 128x64) f16 = 64 KiB -> 2 blocks/CU.
// Grid (16,16,4); masked: skip bx>by -> 544 live blocks over 512 slots.
// ============================================================================
#define SSTG_A(b, kh, tOff) do {                                                \
    char* d_ = (char*)smem + (b) * 32768 + (kh) * 8192 + stgBase;               \
    async_ld16(pA  + (tOff) * 64 + (kh) * 32, d_);                              \
    async_ld16(pA1 + (tOff) * 64 + (kh) * 32, d_ + 4096);                       \
} while (0)
#define SSTG_B(b, kh, tOff) do {                                                \
    char* d_ = (char*)smem + (b) * 32768 + 16384 + (kh) * 8192 + stgBase;       \
    async_ld16(pB  + (tOff) * 64 + (kh) * 32, d_);                              \
    async_ld16(pB1 + (tOff) * 64 + (kh) * 32, d_ + 4096);                       \
} while (0)
#define SRD(b, kk) do {                                                         \
    const char* sa_ = (const char*)smem + (b) * 32768 + (kk) * 8192 + aOff;     \
    _Pragma("unroll") for (int m_ = 0; m_ < 4; ++m_)                            \
        af[m_] = *(const f16x8*)(sa_ + m_ * 1024);                              \
    const char* sb_ = (const char*)smem + (b) * 32768 + 16384 + (kk) * 8192 + bOff; \
    _Pragma("unroll") for (int n_ = 0; n_ < 4; ++n_)                            \
        bf[n_] = *(const f16x8*)(sb_ + n_ * 1024);                              \
} while (0)
#define SFENCE do {                                                             \
    __builtin_amdgcn_s_barrier();                                               \
    asm volatile("s_waitcnt lgkmcnt(0)" ::: "memory");                          \
    __builtin_amdgcn_sched_barrier(0);                                          \
    __builtin_amdgcn_s_setprio(1);                                              \
    _Pragma("unroll") for (int m_ = 0; m_ < 4; ++m_)                            \
        _Pragma("unroll") for (int n_ = 0; n_ < 4; ++n_)                        \
            acc[m_][n_] = __builtin_amdgcn_mfma_f32_16x16x32_f16(af[m_], bf[n_], acc[m_][n_], 0, 0, 0); \
    __builtin_amdgcn_s_setprio(0);                                              \
} while (0)

__global__ __launch_bounds__(256, 2) void scores128(
    const f16* __restrict__ Q, const f16* __restrict__ K,
    f16* __restrict__ P, const int* __restrict__ maskedp)
{
    const int masked = *maskedp;
    const int bx = blockIdx.x, by = blockIdx.y, bz = blockIdx.z;
    if (masked && bx > by) return;
    const int mBase = by * 128, nBase = bx * 128;
    const bool diag = (masked != 0) && (bx == by);

    __shared__ __align__(16) f16 smem[32768];  // 64 KiB
    const int tid = threadIdx.x;
    const int wave = tid >> 6, lane = tid & 63;
    const int wrow = wave >> 1, wcol = wave & 1;
    const int quad = lane >> 4, l16 = lane & 15;
    const int rowLane = tid >> 2;                   // 0..63
    const int cOff = ((tid & 3) ^ ((tid >> 3) & 3)) * 8;
    const int stgBase = wave * 1024;
    const int swz  = (quad ^ ((l16 >> 1) & 3)) * 16;
    const int aOff = (wrow * 64 + l16) * 64 + swz;
    const int bOff = (wcol * 64 + l16) * 64 + swz;

    const f16* Ab = Q + (long)bz * (2048L * 1024);
    const f16* Bb = K + (long)bz * (2048L * 1024);
    const f16* pA  = Ab + (long)(mBase + rowLane) * 1024 + cOff;
    const f16* pA1 = pA + 64 * 1024;
    const f16* pB  = Bb + (long)(nBase + rowLane) * 1024 + cOff;
    const f16* pB1 = pB + 64 * 1024;

    f32x4 acc[4][4];
#pragma unroll
    for (int m = 0; m < 4; ++m)
#pragma unroll
        for (int n = 0; n < 4; ++n) acc[m][n] = (f32x4){0.f, 0.f, 0.f, 0.f};
    f16x8 af[4], bf[4];

    // prologue: tile0 (k0,k1) + tile1 k0 = 12 loads; VMC(4) -> tile0 landed
    SSTG_A(0, 0, 0); SSTG_B(0, 0, 0);
    SSTG_A(0, 1, 0); SSTG_B(0, 1, 0);
    SSTG_A(1, 0, 1); SSTG_B(1, 0, 1);
    VMC(4);
    BAR;

    // 7 iterations x 2 K-tiles + tail 2 = 16 K-tiles (K=1024)
#pragma unroll 1
    for (int i = 0; i < 7; ++i) {
        SRD(0, 0); SSTG_A(1, 1, 1); SSTG_B(1, 1, 1);   // p0: (t+1).k1
        SFENCE; VMC(8); BAR;
        SRD(0, 1); SSTG_A(0, 0, 2); SSTG_B(0, 0, 2);   // p1: (t+2).k0
        SFENCE; VMC(8); BAR;
        SRD(1, 0); SSTG_A(0, 1, 2); SSTG_B(0, 1, 2);   // p2: (t+2).k1
        SFENCE; VMC(8); BAR;
        SRD(1, 1); SSTG_A(1, 0, 3); SSTG_B(1, 0, 3);   // p3: (t+3).k0
        SFENCE; VMC(8); BAR;
        pA += 128; pA1 += 128; pB += 128; pB1 += 128;
    }
    SRD(0, 0); SSTG_A(1, 1, 1); SSTG_B(1, 1, 1);
    SFENCE; VMC(8); BAR;
    SRD(0, 1);
    SFENCE; VMC(4); BAR;
    SRD(1, 0);
    SFENCE; VMC(0); BAR;
    SRD(1, 1);
    SFENCE;

    // ---- epilogue: exp(score/32), causal zero on diag tiles, f16 store ----
    f16* Crow = P + (long)bz * (2048L * 2048);
#pragma unroll
    for (int m = 0; m < 4; ++m)
#pragma unroll
        for (int n = 0; n < 4; ++n)
#pragma unroll
            for (int r = 0; r < 4; ++r) {
                const int row = mBase + wrow * 64 + m * 16 + quad * 4 + r;
                const int col = nBase + wcol * 64 + n * 16 + l16;
                float e = __expf(acc[m][n][r] * 0.03125f);
                if (diag && col > row) e = 0.f;
                Crow[(long)row * 2048 + col] = (f16)e;
            }
}

#undef SSTG_A
#undef SSTG_B
#undef SRD
#undef SFENCE

// ============================================================================
// qkv128 (r19): BM=128 x BN=256, 768 blocks, XCD n-slow/m-fast (r16; FETCH
// 84->49 MB verified). 3 x 24 KiB buffers = 72 KiB LDS -> 2 blocks/CU.
// One phase per 32-col K-step (32 phases): {8 ds_read | stage step t+2
// (3 loads) -> BAR -> lgkm(0) -> 16 MFMA -> VMC(3) -> BAR}.
// Buffer j=s%3: read at phase s; overwritten by stores issued at s+1 (after
// the BAR that follows s's lgkm-drained reads) -> no race.
// LDS map per buffer j (24 KiB at j*24576): A 8 KiB [128r x 32c], B 16 KiB
// [256r x 32c] at +8192 (pB rows 0-127, pB1 rows 128-255 at +8192).
// ============================================================================
#define QSTG(j, o) do {                                                         \
    char* da_ = (char*)smem + (j) * 24576 + wave * 1024;                        \
    async_ld16(pA  + (o) * 32, da_);                                            \
    char* db_ = (char*)smem + (j) * 24576 + 8192 + wave * 1024;                 \
    async_ld16(pB  + (o) * 32, db_);                                            \
    async_ld16(pB1 + (o) * 32, db_ + 8192);                                     \
} while (0)
#define QRD(j) do {                                                             \
    const char* sa_ = (const char*)smem + (j) * 24576 + aOff;                   \
    _Pragma("unroll") for (int m_ = 0; m_ < 4; ++m_)                            \
        af[m_] = *(const f16x8*)(sa_ + m_ * 1024);                              \
    const char* sb_ = (const char*)smem + (j) * 24576 + 8192 + bOff;            \
    _Pragma("unroll") for (int n_ = 0; n_ < 4; ++n_)                            \
        bf[n_] = *(const f16x8*)(sb_ + n_ * 1024);                              \
} while (0)
#define QFENCE do {                                                             \
    __builtin_amdgcn_s_barrier();                                               \
    asm volatile("s_waitcnt lgkmcnt(0)" ::: "memory");                          \
    __builtin_amdgcn_sched_barrier(0);                                          \
    __builtin_amdgcn_s_setprio(1);                                              \
    _Pragma("unroll") for (int m_ = 0; m_ < 4; ++m_)                            \
        _Pragma("unroll") for (int n_ = 0; n_ < 4; ++n_)                        \
            acc[m_][n_] = __builtin_amdgcn_mfma_f32_16x16x32_f16(af[m_], bf[n_], acc[m_][n_], 0, 0, 0); \
    __builtin_amdgcn_s_setprio(0);                                              \
} while (0)
// phase t: read buf j, stage step (t+2) into buf j2 at ptr offset o2 (32-col
// units); VMC(3) -> step t+1 landed (its 3 loads issued one phase back),
// step t+2's 3 stay in flight.
#define QT(j, j2, o2) do { QRD(j); QSTG(j2, o2); QFENCE; VMC(3); BAR; } while (0)

__global__ __launch_bounds__(512, 2) void qkv128(
    const f16* __restrict__ A, const f16* __restrict__ Bt,
    const float* __restrict__ b_q, const float* __restrict__ b_k,
    const float* __restrict__ b_v,
    f16* __restrict__ Q16, f16* __restrict__ K16, f16* __restrict__ Vt16)
{
    // r16: n-slow / m-fast within each XCD's chunk -> W3 N-tile + A-chunk
    // both L2-resident (FETCH 84 -> 49 MB, verified r17).
    const int orig = blockIdx.x;
    const int xcd = orig & 7;
    const int s = orig >> 3;               // 0..95, increasing in time per XCD
    const int by = xcd * 8 + (s & 7);      // M-panel sweeps fast
    const int bx = s >> 3;                 // N-tile slow -> B L2-resident
    const int mBase = by * 128, nBase = bx * 256;

    __shared__ __align__(16) f16 smem[36864];  // 72 KiB: 3 x (A 8K + B 16K)
    const int tid = threadIdx.x;
    const int wave = tid >> 6, lane = tid & 63;
    const int wrow = wave >> 2, wcol = wave & 3;
    const int quad = lane >> 4, l16 = lane & 15;
    const int rowLane = tid >> 2;                   // 0..127
    const int cOff = ((tid & 3) ^ ((tid >> 3) & 3)) * 8;
    const int swz  = (quad ^ ((l16 >> 1) & 3)) * 16;
    const int aOff = (wrow * 64 + l16) * 64 + swz;   // A: 128 rows, 64 B rows
    const int bOff = (wcol * 64 + l16) * 64 + swz;   // B: 256 rows, 64 B rows

    const f16* pA  = A  + (long)(mBase + rowLane) * 1024 + cOff;
    const f16* pB  = Bt + (long)(nBase + rowLane) * 1024 + cOff;
    const f16* pB1 = pB + 128 * 1024;

    f32x4 acc[4][4];
#pragma unroll
    for (int m = 0; m < 4; ++m)
#pragma unroll
        for (int n = 0; n < 4; ++n) acc[m][n] = (f32x4){0.f, 0.f, 0.f, 0.f};
    f16x8 af[4], bf[4];

    // prologue: stage step0 (buf0), step1 (buf1) = 6 loads; VMC(3) -> step0
    QSTG(0, 0); QSTG(1, 1);
    VMC(3);
    BAR;

    // phases t=0..29 in 10 groups of 3 (bufs cycle 0,1,2; stage t+2)
#pragma unroll 1
    for (int g = 0; g < 10; ++g) {
        QT(0, 2, 2);
        QT(1, 0, 3);
        QT(2, 1, 4);
        pA += 96; pB += 96; pB1 += 96;
    }
    // t=30 (buf0): no staging left; VMC(0) -> step31 landed
    QRD(0); QFENCE; VMC(0); BAR;
    // t=31 (buf1)
    QRD(1); QFENCE;
    BAR;   // guard smem reuse in V epilogue

    // ---- epilogue. C/D layout: col = lane&15, row = quad*4 + reg  [m89] ----
    const int seg = nBase >> 10;
    const float* bs = (seg == 0) ? b_q : (seg == 1) ? b_k : b_v;
    const int lcb = (nBase & 1023) + wcol * 64;
    float bvv[4];
#pragma unroll
    for (int n = 0; n < 4; ++n) bvv[n] = bs[lcb + n * 16 + l16];

    if (seg < 2) {
        f16* dst = (seg == 0) ? Q16 : K16;
#pragma unroll
        for (int m = 0; m < 4; ++m)
#pragma unroll
            for (int n = 0; n < 4; ++n)
#pragma unroll
                for (int r = 0; r < 4; ++r) {
                    const int row = mBase + wrow * 64 + m * 16 + quad * 4 + r;
                    dst[(long)row * 1024 + lcb + n * 16 + l16] =
                        (f16)(acc[m][n][r] + bvv[n]);
                }
    } else {
        // V: per-wave transpose through private LDS (64 e x 72 f16), then
        // 256 B per e-row-quarter stores along s. Intra-wave only.
        const int b = mBase >> 11;
        const int s0 = (mBase & 2047) + wrow * 64;
        const int e0 = (nBase & 1023) + wcol * 64;
        f16* epiW = smem + wave * (64 * 72);   // 8 x 9216 B = 72 KiB exactly
#pragma unroll
        for (int m = 0; m < 4; ++m)
#pragma unroll
            for (int n = 0; n < 4; ++n) {
                f16x4v pk;
#pragma unroll
                for (int r = 0; r < 4; ++r)
                    pk[r] = (f16)(acc[m][n][r] + bvv[n]);
                *(f16x4v*)&epiW[(n * 16 + l16) * 72 + m * 16 + quad * 4] = pk;
            }
        asm volatile("s_waitcnt lgkmcnt(0)" ::: "memory");
#pragma unroll
        for (int it = 0; it < 8; ++it) {
            const int e = it * 8 + (lane >> 3);
            const f16x8 v = *(const f16x8*)&epiW[e * 72 + (lane & 7) * 8];
            *(f16x8*)(Vt16 + ((long)b * 1024 + e0 + e) * 2048 + s0 +
                      (lane & 7) * 8) = v;
        }
    }
}

#undef QSTG
#undef QRD
#undef QFENCE
#undef QT

// ============================================================================
// pv128 (r14 pairing, r16 128-granular causal limit, grid (8,16,4)).
// out[b][q][e] = (P @ V) / rowsum[q]; rowsum inline from P A-fragments.
// nIter = by+1; co-resident pair (k, k+256) sums nIter = 17 for all pairs.
// ============================================================================
#if defined(__has_builtin)
#if __has_builtin(__builtin_amdgcn_fdot2)
#define HAVE_FDOT2 1
#endif
#endif

#ifdef HAVE_FDOT2
#define PSUM do {                                                               \
    const f16x2v one_ = {(f16)1, (f16)1};                                       \
    _Pragma("unroll") for (int m_ = 0; m_ < 4; ++m_) {                          \
        const f16x2v* ph_ = (const f16x2v*)&af[m_];                             \
        _Pragma("unroll") for (int j_ = 0; j_ < 4; ++j_)                        \
            rs[m_] = __builtin_amdgcn_fdot2(ph_[j_], one_, rs[m_], false);      \
    }                                                                           \
} while (0)
#else
#define PSUM do {                                                               \
    _Pragma("unroll") for (int m_ = 0; m_ < 4; ++m_)                            \
        _Pragma("unroll") for (int j_ = 0; j_ < 8; ++j_)                        \
            rs[m_] += (float)af[m_][j_];                                        \
} while (0)
#endif

#define PSTG_A(b, kh, tOff) do {                                                \
    char* d_ = (char*)smem + (b) * 32768 + (kh) * 8192 + stgBase;               \
    async_ld16(pA  + (tOff) * 64 + (kh) * 32, d_);                              \
    async_ld16(pA1 + (tOff) * 64 + (kh) * 32, d_ + 4096);                       \
} while (0)
#define PSTG_B(b, kh, tOff) do {                                                \
    char* d_ = (char*)smem + (b) * 32768 + 16384 + (kh) * 8192 + stgBase;       \
    async_ld16(pB  + (tOff) * 64 + (kh) * 32, d_);                              \
    async_ld16(pB1 + (tOff) * 64 + (kh) * 32, d_ + 4096);                       \
} while (0)
#define PRD(b, kk) do {                                                         \
    const char* sa_ = (const char*)smem + (b) * 32768 + (kk) * 8192 + aOff;     \
    _Pragma("unroll") for (int m_ = 0; m_ < 4; ++m_)                            \
        af[m_] = *(const f16x8*)(sa_ + m_ * 1024);                              \
    const char* sb_ = (const char*)smem + (b) * 32768 + 16384 + (kk) * 8192 + bOff; \
    _Pragma("unroll") for (int n_ = 0; n_ < 4; ++n_)                            \
        bf[n_] = *(const f16x8*)(sb_ + n_ * 1024);                              \
} while (0)
#define PFENCE do {                                                             \
    __builtin_amdgcn_s_barrier();                                               \
    asm volatile("s_waitcnt lgkmcnt(0)" ::: "memory");                          \
    __builtin_amdgcn_sched_barrier(0);                                          \
    __builtin_amdgcn_s_setprio(1);                                              \
    _Pragma("unroll") for (int m_ = 0; m_ < 4; ++m_)                            \
        _Pragma("unroll") for (int n_ = 0; n_ < 4; ++n_)                        \
            acc[m_][n_] = __builtin_amdgcn_mfma_f32_16x16x32_f16(af[m_], bf[n_], acc[m_][n_], 0, 0, 0); \
    __builtin_amdgcn_s_setprio(0);                                              \
    PSUM;                                                                       \
} while (0)

__global__ __launch_bounds__(256, 2) void pv128(
    const f16* __restrict__ P, const f16* __restrict__ Vt,
    float* __restrict__ out, const int* __restrict__ maskedp)
{
    const int masked = *maskedp;
    const int bx = blockIdx.x, bz = blockIdx.z;   // bx in [0,8): E tiles
    const int by = (bz >= 2) ? blockIdx.y : (gridDim.y - 1 - blockIdx.y);
    const int mBase = by * 128, nBase = bx * 128;
    const int nIter = masked ? (by + 1) : 16;   // 128-col steps, >= 1

    __shared__ __align__(16) f16 smem[32768];  // 64 KiB
    const int tid = threadIdx.x;
    const int wave = tid >> 6, lane = tid & 63;
    const int wrow = wave >> 1, wcol = wave & 1;
    const int quad = lane >> 4, l16 = lane & 15;
    const int rowLane = tid >> 2;                   // 0..63
    const int cOff = ((tid & 3) ^ ((tid >> 3) & 3)) * 8;
    const int stgBase = wave * 1024;
    const int swz  = (quad ^ ((l16 >> 1) & 3)) * 16;
    const int aOff = (wrow * 64 + l16) * 64 + swz;
    const int bOff = (wcol * 64 + l16) * 64 + swz;

    const f16* Pb = P  + (long)bz * (2048L * 2048);
    const f16* Vb = Vt + (long)bz * (1024L * 2048);
    const f16* pA  = Pb + (long)(mBase + rowLane) * 2048 + cOff;
    const f16* pA1 = pA + 64 * 2048;
    const f16* pB  = Vb + (long)(nBase + rowLane) * 2048 + cOff;
    const f16* pB1 = pB + 64 * 2048;

    f32x4 acc[4][4];
#pragma unroll
    for (int m = 0; m < 4; ++m)
#pragma unroll
        for (int n = 0; n < 4; ++n) acc[m][n] = (f32x4){0.f, 0.f, 0.f, 0.f};
    f16x8 af[4], bf[4];
    float rs[4] = {0.f, 0.f, 0.f, 0.f};   // rowsum partials, row = m*16+l16

    PSTG_A(0, 0, 0); PSTG_B(0, 0, 0);
    PSTG_A(0, 1, 0); PSTG_B(0, 1, 0);
    PSTG_A(1, 0, 1); PSTG_B(1, 0, 1);
    VMC(4);
    BAR;

#pragma unroll 1
    for (int i = 0; i < nIter - 1; ++i) {
        PRD(0, 0); PSTG_A(1, 1, 1); PSTG_B(1, 1, 1);   // p0: (t+1).k1
        PFENCE; VMC(8); BAR;
        PRD(0, 1); PSTG_A(0, 0, 2); PSTG_B(0, 0, 2);   // p1: (t+2).k0
        PFENCE; VMC(8); BAR;
        PRD(1, 0); PSTG_A(0, 1, 2); PSTG_B(0, 1, 2);   // p2: (t+2).k1
        PFENCE; VMC(8); BAR;
        PRD(1, 1); PSTG_A(1, 0, 3); PSTG_B(1, 0, 3);   // p3: (t+3).k0
        PFENCE; VMC(8); BAR;
        pA += 128; pA1 += 128; pB += 128; pB1 += 128;
    }
    PRD(0, 0); PSTG_A(1, 1, 1); PSTG_B(1, 1, 1);
    PFENCE; VMC(8); BAR;
    PRD(0, 1);
    PFENCE; VMC(4); BAR;
    PRD(1, 0);
    PFENCE; VMC(0); BAR;
    PRD(1, 1);
    PFENCE;

    // ---- rowsum completion: quad reduce; all lanes get row m*16+l16 sum ---
#pragma unroll
    for (int m = 0; m < 4; ++m) {
        rs[m] += __shfl_xor(rs[m], 16);
        rs[m] += __shfl_xor(rs[m], 32);
    }

    // ---- epilogue: out = acc / rowsum[row]; rowsum for row quad*4+r lives
    // in lane l16 = quad*4+r ----
    float* ob = out + (long)bz * (2048L * 1024);
#pragma unroll
    for (int m = 0; m < 4; ++m)
#pragma unroll
        for (int r = 0; r < 4; ++r) {
            const int row = mBase + wrow * 64 + m * 16 + quad * 4 + r;
            const float inv = 1.f / __shfl(rs[m], quad * 4 + r);
#pragma unroll
            for (int n = 0; n < 4; ++n) {
                const int col = nBase + wcol * 64 + n * 16 + l16;
                ob[(long)row * 1024 + col] = acc[m][n][r] * inv;
            }
        }
}

#undef PSTG_A
#undef PSTG_B
#undef PRD
#undef PFENCE
#undef PSUM
#undef VMC
#undef BAR

// ============================================================================
// r13: merged input/weight conversion.
// Blocks [0, 8192): inp f32 -> f16 (8192x1024). Blocks [8192, 11264): the
// three 1024x1024 weights -> contiguous f16 [3072][1024].
// ============================================================================
__global__ void cvt_all(const float* __restrict__ inp,
                        const float* __restrict__ W0,
                        const float* __restrict__ W1,
                        const float* __restrict__ W2,
                        f16* __restrict__ inp16, f16* __restrict__ W3)
{
    const int bxx = blockIdx.x;
    const float* src;
    f16* dst;
    int i;
    if (bxx < 8192) {
        src = inp; dst = inp16;
        i = bxx * 256 + threadIdx.x;
    } else {
        const int wb = bxx - 8192;          // 0..3071
        const int which = wb >> 10;
        src = (which == 0) ? W0 : (which == 1) ? W1 : W2;
        dst = W3 + (long)which * 1024 * 1024;
        i = (wb & 1023) * 256 + threadIdx.x;
    }
    const float4 v = ((const float4*)src)[i];
    f16x4v o;
    o[0] = (f16)v.x; o[1] = (f16)v.y; o[2] = (f16)v.z; o[3] = (f16)v.w;
    ((f16x4v*)dst)[i] = o;
}

extern "C" void kernel_launch(void* const* d_in, const int* in_sizes, int n_in,
                              void* d_out, int out_size, void* d_ws, size_t ws_size,
                              hipStream_t stream)
{
    const float* inp = (const float*)d_in[0];
    const int* masked = (const int*)d_in[1];
    const float* Wq = (const float*)d_in[2];
    const float* bq = (const float*)d_in[3];
    const float* Wk = (const float*)d_in[4];
    const float* bk = (const float*)d_in[5];
    const float* Wv = (const float*)d_in[6];
    const float* bv = (const float*)d_in[7];
    float* out = (float*)d_out;

    const int S = 2048, E = 1024;
    const long nTok = (long)4 * S;    // 8192

    // workspace (~102 MB). W3 segments must stay contiguous (one Bt operand).
    char* ws = (char*)d_ws;
    f16* inp16 = (f16*)ws;   ws += nTok * E * 2;         // 16 MB
    f16* W3    = (f16*)ws;   ws += (long)3 * E * E * 2;  //  6 MB
    f16* Q16   = (f16*)ws;   ws += nTok * E * 2;         // 16 MB
    f16* K16   = (f16*)ws;   ws += nTok * E * 2;         // 16 MB
    f16* Vt16  = (f16*)ws;   ws += nTok * E * 2;         // 16 MB ([b][e][s])
    f16* P16   = (f16*)ws;   ws += (long)4 * S * S * 2;  // 32 MB

    // f32 -> f16 conversions (one dispatch)
    cvt_all<<<dim3(8192 + 3072), dim3(256), 0, stream>>>(
        inp, Wq, Wk, Wv, inp16, W3);

    // fused QKV: 128x256-tile, 768 blocks, 72 KiB LDS -> 2 blocks/CU,
    // 3-buffer 1-step-per-phase schedule (r19), L2-resident XCD order (r16)
    qkv128<<<dim3(768), dim3(512), 0, stream>>>(
        inp16, W3, bq, bk, bv, Q16, K16, Vt16);

    // P = exp(QK^T/32): 128x128-tile 4-phase, 2 blocks/CU (r16)
    scores128<<<dim3(16, 16, 4), dim3(256), 0, stream>>>(
        Q16, K16, P16, masked);

    // out = (P @ V)/rowsum: 128x128-tile 4-phase, balanced pairing,
    // 128-granular causal K-limit, grid (8,16,4) (r17)
    pv128<<<dim3(8, 16, 4), dim3(256), 0, stream>>>(
        P16, Vt16, out, masked);
}

// Round 14
// 220.258 us; speedup vs baseline: 1.0579x; 1.0579x over previous
//
#include <hip/hip_runtime.h>

typedef _Float16 f16;
typedef f16 f16x8 __attribute__((ext_vector_type(8)));
typedef f16 f16x4v __attribute__((ext_vector_type(4)));
typedef f16 f16x2v __attribute__((ext_vector_type(2)));
typedef float f32x4 __attribute__((ext_vector_type(4)));

// async global->LDS, 16B per lane. LDS dest is wave-uniform base; HW scatters
// lane i's 16B to base + i*16. lane = WITHIN-WAVE lane (0..63) -> multi-wave
// staging MUST offset the dest by wave (r20's NaN: missing wave*1024).
__device__ __forceinline__ void async_ld16(const void* g, void* l) {
    __builtin_amdgcn_global_load_lds(
        (const __attribute__((address_space(1))) unsigned int*)g,
        (__attribute__((address_space(3))) unsigned int*)l, 16, 0, 0);
}

#define VMC(n) asm volatile("s_waitcnt vmcnt(" #n ")" ::: "memory")
#define BAR __builtin_amdgcn_s_barrier()

// ============================================================================
// r21 = r20 with the staging-destination fix (+ wave*1024 in QSTG; r20 wrote
// all 4 waves to the same 1 KB slice -> stale A/B -> NaN).
// r20 theory under test: qkv wave-retile 64x64 -> 128x64 cuts LDS reads to
// 0.375 b128/MFMA (12 per 32), per-phase LDS 88->72 KB, floor 41->34 us.
// 4 waves (256 thr), tile 128x256, 768 blocks = 3 rounds, 3 x 24 KiB buffers
// (72 KiB -> 2 blocks/CU), 1 phase per 32-col K-step, VMC(6)/phase,
// K-order unchanged -> bit-identical outputs.
// ============================================================================

// ============================================================================
// scores128: P[b][q][k] = exp((Q.K^T)/32) f16, causal-zeroed.
// BM=BN=128, BK=64, 256 thr = 4 waves (2M x 2N), wave C = 64x64 = 4x4 frags.
// LDS = 2 buf x (A 128x64 + B 128x64) f16 = 64 KiB -> 2 blocks/CU.
// Grid (16,16,4); masked: skip bx>by -> 544 live blocks over 512 slots.
// ============================================================================
#define SSTG_A(b, kh, tOff) do {                                                \
    char* d_ = (char*)smem + (b) * 32768 + (kh) * 8192 + stgBase;               \
    async_ld16(pA  + (tOff) * 64 + (kh) * 32, d_);                              \
    async_ld16(pA1 + (tOff) * 64 + (kh) * 32, d_ + 4096);                       \
} while (0)
#define SSTG_B(b, kh, tOff) do {                                                \
    char* d_ = (char*)smem + (b) * 32768 + 16384 + (kh) * 8192 + stgBase;       \
    async_ld16(pB  + (tOff) * 64 + (kh) * 32, d_);                              \
    async_ld16(pB1 + (tOff) * 64 + (kh) * 32, d_ + 4096);                       \
} while (0)
#define SRD(b, kk) do {                                                         \
    const char* sa_ = (const char*)smem + (b) * 32768 + (kk) * 8192 + aOff;     \
    _Pragma("unroll") for (int m_ = 0; m_ < 4; ++m_)                            \
        af[m_] = *(const f16x8*)(sa_ + m_ * 1024);                              \
    const char* sb_ = (const char*)smem + (b) * 32768 + 16384 + (kk) * 8192 + bOff; \
    _Pragma("unroll") for (int n_ = 0; n_ < 4; ++n_)                            \
        bf[n_] = *(const f16x8*)(sb_ + n_ * 1024);                              \
} while (0)
#define SFENCE do {                                                             \
    __builtin_amdgcn_s_barrier();                                               \
    asm volatile("s_waitcnt lgkmcnt(0)" ::: "memory");                          \
    __builtin_amdgcn_sched_barrier(0);                                          \
    __builtin_amdgcn_s_setprio(1);                                              \
    _Pragma("unroll") for (int m_ = 0; m_ < 4; ++m_)                            \
        _Pragma("unroll") for (int n_ = 0; n_ < 4; ++n_)                        \
            acc[m_][n_] = __builtin_amdgcn_mfma_f32_16x16x32_f16(af[m_], bf[n_], acc[m_][n_], 0, 0, 0); \
    __builtin_amdgcn_s_setprio(0);                                              \
} while (0)

__global__ __launch_bounds__(256, 2) void scores128(
    const f16* __restrict__ Q, const f16* __restrict__ K,
    f16* __restrict__ P, const int* __restrict__ maskedp)
{
    const int masked = *maskedp;
    const int bx = blockIdx.x, by = blockIdx.y, bz = blockIdx.z;
    if (masked && bx > by) return;
    const int mBase = by * 128, nBase = bx * 128;
    const bool diag = (masked != 0) && (bx == by);

    __shared__ __align__(16) f16 smem[32768];  // 64 KiB
    const int tid = threadIdx.x;
    const int wave = tid >> 6, lane = tid & 63;
    const int wrow = wave >> 1, wcol = wave & 1;
    const int quad = lane >> 4, l16 = lane & 15;
    const int rowLane = tid >> 2;                   // 0..63
    const int cOff = ((tid & 3) ^ ((tid >> 3) & 3)) * 8;
    const int stgBase = wave * 1024;
    const int swz  = (quad ^ ((l16 >> 1) & 3)) * 16;
    const int aOff = (wrow * 64 + l16) * 64 + swz;
    const int bOff = (wcol * 64 + l16) * 64 + swz;

    const f16* Ab = Q + (long)bz * (2048L * 1024);
    const f16* Bb = K + (long)bz * (2048L * 1024);
    const f16* pA  = Ab + (long)(mBase + rowLane) * 1024 + cOff;
    const f16* pA1 = pA + 64 * 1024;
    const f16* pB  = Bb + (long)(nBase + rowLane) * 1024 + cOff;
    const f16* pB1 = pB + 64 * 1024;

    f32x4 acc[4][4];
#pragma unroll
    for (int m = 0; m < 4; ++m)
#pragma unroll
        for (int n = 0; n < 4; ++n) acc[m][n] = (f32x4){0.f, 0.f, 0.f, 0.f};
    f16x8 af[4], bf[4];

    // prologue: tile0 (k0,k1) + tile1 k0 = 12 loads; VMC(4) -> tile0 landed
    SSTG_A(0, 0, 0); SSTG_B(0, 0, 0);
    SSTG_A(0, 1, 0); SSTG_B(0, 1, 0);
    SSTG_A(1, 0, 1); SSTG_B(1, 0, 1);
    VMC(4);
    BAR;

    // 7 iterations x 2 K-tiles + tail 2 = 16 K-tiles (K=1024)
#pragma unroll 1
    for (int i = 0; i < 7; ++i) {
        SRD(0, 0); SSTG_A(1, 1, 1); SSTG_B(1, 1, 1);   // p0: (t+1).k1
        SFENCE; VMC(8); BAR;
        SRD(0, 1); SSTG_A(0, 0, 2); SSTG_B(0, 0, 2);   // p1: (t+2).k0
        SFENCE; VMC(8); BAR;
        SRD(1, 0); SSTG_A(0, 1, 2); SSTG_B(0, 1, 2);   // p2: (t+2).k1
        SFENCE; VMC(8); BAR;
        SRD(1, 1); SSTG_A(1, 0, 3); SSTG_B(1, 0, 3);   // p3: (t+3).k0
        SFENCE; VMC(8); BAR;
        pA += 128; pA1 += 128; pB += 128; pB1 += 128;
    }
    SRD(0, 0); SSTG_A(1, 1, 1); SSTG_B(1, 1, 1);
    SFENCE; VMC(8); BAR;
    SRD(0, 1);
    SFENCE; VMC(4); BAR;
    SRD(1, 0);
    SFENCE; VMC(0); BAR;
    SRD(1, 1);
    SFENCE;

    // ---- epilogue: exp(score/32), causal zero on diag tiles, f16 store ----
    f16* Crow = P + (long)bz * (2048L * 2048);
#pragma unroll
    for (int m = 0; m < 4; ++m)
#pragma unroll
        for (int n = 0; n < 4; ++n)
#pragma unroll
            for (int r = 0; r < 4; ++r) {
                const int row = mBase + wrow * 64 + m * 16 + quad * 4 + r;
                const int col = nBase + wcol * 64 + n * 16 + l16;
                float e = __expf(acc[m][n][r] * 0.03125f);
                if (diag && col > row) e = 0.f;
                Crow[(long)row * 2048 + col] = (f16)e;
            }
}

#undef SSTG_A
#undef SSTG_B
#undef SRD
#undef SFENCE

// ============================================================================
// qkv128 (r21): BM=128 x BN=256, 768 blocks = 3 exact rounds, XCD n-slow/
// m-fast ordering (r16; FETCH 84->49 MB verified). 256 thr = 4 waves of
// 128x64 (8m x 4n frags, 32 MFMA / 12 ds_read per phase). 3 x 24 KiB
// buffers = 72 KiB -> 2 blocks/CU. One phase per 32-col K-step:
// {12 ds_read | stage step t+2 (6 calls) -> BAR -> lgkm(0) -> 32 MFMA ->
// VMC(6) -> BAR}. LDS buffer j at j*24576: A 8 KiB [128r x 64B], B 16 KiB
// [256r x 64B] at +8192. Staging: per call, wave w covers 16 rows -> dest
// + w*1024 (within-wave lane scatter only!); row = tid>>2, source unit
// c = (tid&3) ^ ((tid>>3)&3) (consistent per wave: 16-row groups preserve
// (row>>1)&3 = (l>>3)&3).
// ============================================================================
#define QSTG(j, o) do {                                                         \
    char* da_ = (char*)smem + (j) * 24576 + wave * 1024;                        \
    async_ld16(pA0 + (o) * 32, da_);                                            \
    async_ld16(pA1 + (o) * 32, da_ + 4096);                                     \
    char* db_ = (char*)smem + (j) * 24576 + 8192 + wave * 1024;                 \
    async_ld16(pB0 + (o) * 32, db_);                                            \
    async_ld16(pB1 + (o) * 32, db_ + 4096);                                     \
    async_ld16(pB2 + (o) * 32, db_ + 8192);                                     \
    async_ld16(pB3 + (o) * 32, db_ + 12288);                                    \
} while (0)
#define QRD(j) do {                                                             \
    const char* sa_ = (const char*)smem + (j) * 24576 + aOff;                   \
    _Pragma("unroll") for (int m_ = 0; m_ < 8; ++m_)                            \
        af[m_] = *(const f16x8*)(sa_ + m_ * 1024);                              \
    const char* sb_ = (const char*)smem + (j) * 24576 + 8192 + bOff;            \
    _Pragma("unroll") for (int n_ = 0; n_ < 4; ++n_)                            \
        bf[n_] = *(const f16x8*)(sb_ + n_ * 1024);                              \
} while (0)
#define QFENCE do {                                                             \
    __builtin_amdgcn_s_barrier();                                               \
    asm volatile("s_waitcnt lgkmcnt(0)" ::: "memory");                          \
    __builtin_amdgcn_sched_barrier(0);                                          \
    __builtin_amdgcn_s_setprio(1);                                              \
    _Pragma("unroll") for (int m_ = 0; m_ < 8; ++m_)                            \
        _Pragma("unroll") for (int n_ = 0; n_ < 4; ++n_)                        \
            acc[m_][n_] = __builtin_amdgcn_mfma_f32_16x16x32_f16(af[m_], bf[n_], acc[m_][n_], 0, 0, 0); \
    __builtin_amdgcn_s_setprio(0);                                              \
} while (0)
#define QT(j, j2, o2) do { QRD(j); QSTG(j2, o2); QFENCE; VMC(6); BAR; } while (0)

__global__ __launch_bounds__(256, 2) void qkv128(
    const f16* __restrict__ A, const f16* __restrict__ Bt,
    const float* __restrict__ b_q, const float* __restrict__ b_k,
    const float* __restrict__ b_v,
    f16* __restrict__ Q16, f16* __restrict__ K16, f16* __restrict__ Vt16)
{
    const int orig = blockIdx.x;
    const int xcd = orig & 7;
    const int s = orig >> 3;               // 0..95, increasing in time per XCD
    const int by = xcd * 8 + (s & 7);      // M-panel sweeps fast
    const int bx = s >> 3;                 // N-tile slow -> B L2-resident
    const int mBase = by * 128, nBase = bx * 256;

    __shared__ __align__(16) f16 smem[36864];  // 72 KiB: 3 x (A 8K + B 16K)
    const int tid = threadIdx.x;
    const int wave = tid >> 6, lane = tid & 63;
    const int quad = lane >> 4, l16 = lane & 15;
    const int rowLane = tid >> 2;                   // 0..63 (staging row)
    const int cOff = ((tid & 3) ^ ((tid >> 3) & 3)) * 8;
    const int swz  = (quad ^ ((l16 >> 1) & 3)) * 16;
    const int aOff = l16 * 64 + swz;                 // + m*16*64 per frag
    const int bOff = (wave * 64 + l16) * 64 + swz;   // wave owns 64 n-cols

    const f16* pA0 = A  + (long)(mBase + rowLane) * 1024 + cOff;
    const f16* pA1 = pA0 + 64 * 1024;
    const f16* pB0 = Bt + (long)(nBase + rowLane) * 1024 + cOff;
    const f16* pB1 = pB0 + 64 * 1024;
    const f16* pB2 = pB0 + 128 * 1024;
    const f16* pB3 = pB0 + 192 * 1024;

    f32x4 acc[8][4];
#pragma unroll
    for (int m = 0; m < 8; ++m)
#pragma unroll
        for (int n = 0; n < 4; ++n) acc[m][n] = (f32x4){0.f, 0.f, 0.f, 0.f};
    f16x8 af[8], bf[4];

    // prologue: stage step0 (buf0), step1 (buf1) = 12 calls; VMC(6) -> step0
    QSTG(0, 0); QSTG(1, 1);
    VMC(6);
    BAR;

    // phases t=0..29 in 10 groups of 3 (bufs cycle 0,1,2; stage t+2)
#pragma unroll 1
    for (int g = 0; g < 10; ++g) {
        QT(0, 2, 2);
        QT(1, 0, 3);
        QT(2, 1, 4);
        pA0 += 96; pA1 += 96; pB0 += 96; pB1 += 96; pB2 += 96; pB3 += 96;
    }
    // t=30 (buf0): nothing left to stage; VMC(0) -> step31 landed
    QRD(0); QFENCE; VMC(0); BAR;
    // t=31 (buf1)
    QRD(1); QFENCE;
    BAR;   // guard smem reuse in V epilogue

    // ---- epilogue. C/D layout: col = lane&15, row = quad*4 + reg  [m89] ----
    const int seg = nBase >> 10;
    const float* bs = (seg == 0) ? b_q : (seg == 1) ? b_k : b_v;
    const int lcb = (nBase & 1023) + wave * 64;
    float bvv[4];
#pragma unroll
    for (int n = 0; n < 4; ++n) bvv[n] = bs[lcb + n * 16 + l16];

    if (seg < 2) {
        f16* dst = (seg == 0) ? Q16 : K16;
#pragma unroll
        for (int m = 0; m < 8; ++m)
#pragma unroll
            for (int n = 0; n < 4; ++n)
#pragma unroll
                for (int r = 0; r < 4; ++r) {
                    const int row = mBase + m * 16 + quad * 4 + r;
                    dst[(long)row * 1024 + lcb + n * 16 + l16] =
                        (f16)(acc[m][n][r] + bvv[n]);
                }
    } else {
        // V: per-wave transpose through private LDS (64 e x 136 f16 stride,
        // 17408 B/wave x 4 = 69632 <= 73728), then f16x8 stores along s.
        const int b = mBase >> 11;
        const int s0 = mBase & 2047;
        const int e0 = (nBase & 1023) + wave * 64;
        f16* epiW = smem + wave * (64 * 136);
#pragma unroll
        for (int m = 0; m < 8; ++m)
#pragma unroll
            for (int n = 0; n < 4; ++n) {
                f16x4v pk;
#pragma unroll
                for (int r = 0; r < 4; ++r)
                    pk[r] = (f16)(acc[m][n][r] + bvv[n]);
                *(f16x4v*)&epiW[(n * 16 + l16) * 136 + m * 16 + quad * 4] = pk;
            }
        asm volatile("s_waitcnt lgkmcnt(0)" ::: "memory");
#pragma unroll
        for (int it = 0; it < 16; ++it) {
            const int e = it * 4 + (lane >> 4);
            const f16x8 v = *(const f16x8*)&epiW[e * 136 + (lane & 15) * 8];
            *(f16x8*)(Vt16 + ((long)b * 1024 + e0 + e) * 2048 + s0 +
                      (lane & 15) * 8) = v;
        }
    }
}

#undef QSTG
#undef QRD
#undef QFENCE
#undef QT

// ============================================================================
// pv128 (r14 pairing, r16 128-granular causal limit, grid (8,16,4)).
// out[b][q][e] = (P @ V) / rowsum[q]; rowsum inline from P A-fragments.
// nIter = by+1; co-resident pair (k, k+256) sums nIter = 17 for all pairs.
// ============================================================================
#if defined(__has_builtin)
#if __has_builtin(__builtin_amdgcn_fdot2)
#define HAVE_FDOT2 1
#endif
#endif

#ifdef HAVE_FDOT2
#define PSUM do {                                                               \
    const f16x2v one_ = {(f16)1, (f16)1};                                       \
    _Pragma("unroll") for (int m_ = 0; m_ < 4; ++m_) {                          \
        const f16x2v* ph_ = (const f16x2v*)&af[m_];                             \
        _Pragma("unroll") for (int j_ = 0; j_ < 4; ++j_)                        \
            rs[m_] = __builtin_amdgcn_fdot2(ph_[j_], one_, rs[m_], false);      \
    }                                                                           \
} while (0)
#else
#define PSUM do {                                                               \
    _Pragma("unroll") for (int m_ = 0; m_ < 4; ++m_)                            \
        _Pragma("unroll") for (int j_ = 0; j_ < 8; ++j_)                        \
            rs[m_] += (float)af[m_][j_];                                        \
} while (0)
#endif

#define PSTG_A(b, kh, tOff) do {                                                \
    char* d_ = (char*)smem + (b) * 32768 + (kh) * 8192 + stgBase;               \
    async_ld16(pA  + (tOff) * 64 + (kh) * 32, d_);                              \
    async_ld16(pA1 + (tOff) * 64 + (kh) * 32, d_ + 4096);                       \
} while (0)
#define PSTG_B(b, kh, tOff) do {                                                \
    char* d_ = (char*)smem + (b) * 32768 + 16384 + (kh) * 8192 + stgBase;       \
    async_ld16(pB  + (tOff) * 64 + (kh) * 32, d_);                              \
    async_ld16(pB1 + (tOff) * 64 + (kh) * 32, d_ + 4096);                       \
} while (0)
#define PRD(b, kk) do {                                                         \
    const char* sa_ = (const char*)smem + (b) * 32768 + (kk) * 8192 + aOff;     \
    _Pragma("unroll") for (int m_ = 0; m_ < 4; ++m_)                            \
        af[m_] = *(const f16x8*)(sa_ + m_ * 1024);                              \
    const char* sb_ = (const char*)smem + (b) * 32768 + 16384 + (kk) * 8192 + bOff; \
    _Pragma("unroll") for (int n_ = 0; n_ < 4; ++n_)                            \
        bf[n_] = *(const f16x8*)(sb_ + n_ * 1024);                              \
} while (0)
#define PFENCE do {                                                             \
    __builtin_amdgcn_s_barrier();                                               \
    asm volatile("s_waitcnt lgkmcnt(0)" ::: "memory");                          \
    __builtin_amdgcn_sched_barrier(0);                                          \
    __builtin_amdgcn_s_setprio(1);                                              \
    _Pragma("unroll") for (int m_ = 0; m_ < 4; ++m_)                            \
        _Pragma("unroll") for (int n_ = 0; n_ < 4; ++n_)                        \
            acc[m_][n_] = __builtin_amdgcn_mfma_f32_16x16x32_f16(af[m_], bf[n_], acc[m_][n_], 0, 0, 0); \
    __builtin_amdgcn_s_setprio(0);                                              \
    PSUM;                                                                       \
} while (0)

__global__ __launch_bounds__(256, 2) void pv128(
    const f16* __restrict__ P, const f16* __restrict__ Vt,
    float* __restrict__ out, const int* __restrict__ maskedp)
{
    const int masked = *maskedp;
    const int bx = blockIdx.x, bz = blockIdx.z;   // bx in [0,8): E tiles
    const int by = (bz >= 2) ? blockIdx.y : (gridDim.y - 1 - blockIdx.y);
    const int mBase = by * 128, nBase = bx * 128;
    const int nIter = masked ? (by + 1) : 16;   // 128-col steps, >= 1

    __shared__ __align__(16) f16 smem[32768];  // 64 KiB
    const int tid = threadIdx.x;
    const int wave = tid >> 6, lane = tid & 63;
    const int wrow = wave >> 1, wcol = wave & 1;
    const int quad = lane >> 4, l16 = lane & 15;
    const int rowLane = tid >> 2;                   // 0..63
    const int cOff = ((tid & 3) ^ ((tid >> 3) & 3)) * 8;
    const int stgBase = wave * 1024;
    const int swz  = (quad ^ ((l16 >> 1) & 3)) * 16;
    const int aOff = (wrow * 64 + l16) * 64 + swz;
    const int bOff = (wcol * 64 + l16) * 64 + swz;

    const f16* Pb = P  + (long)bz * (2048L * 2048);
    const f16* Vb = Vt + (long)bz * (1024L * 2048);
    const f16* pA  = Pb + (long)(mBase + rowLane) * 2048 + cOff;
    const f16* pA1 = pA + 64 * 2048;
    const f16* pB  = Vb + (long)(nBase + rowLane) * 2048 + cOff;
    const f16* pB1 = pB + 64 * 2048;

    f32x4 acc[4][4];
#pragma unroll
    for (int m = 0; m < 4; ++m)
#pragma unroll
        for (int n = 0; n < 4; ++n) acc[m][n] = (f32x4){0.f, 0.f, 0.f, 0.f};
    f16x8 af[4], bf[4];
    float rs[4] = {0.f, 0.f, 0.f, 0.f};   // rowsum partials, row = m*16+l16

    PSTG_A(0, 0, 0); PSTG_B(0, 0, 0);
    PSTG_A(0, 1, 0); PSTG_B(0, 1, 0);
    PSTG_A(1, 0, 1); PSTG_B(1, 0, 1);
    VMC(4);
    BAR;

#pragma unroll 1
    for (int i = 0; i < nIter - 1; ++i) {
        PRD(0, 0); PSTG_A(1, 1, 1); PSTG_B(1, 1, 1);   // p0: (t+1).k1
        PFENCE; VMC(8); BAR;
        PRD(0, 1); PSTG_A(0, 0, 2); PSTG_B(0, 0, 2);   // p1: (t+2).k0
        PFENCE; VMC(8); BAR;
        PRD(1, 0); PSTG_A(0, 1, 2); PSTG_B(0, 1, 2);   // p2: (t+2).k1
        PFENCE; VMC(8); BAR;
        PRD(1, 1); PSTG_A(1, 0, 3); PSTG_B(1, 0, 3);   // p3: (t+3).k0
        PFENCE; VMC(8); BAR;
        pA += 128; pA1 += 128; pB += 128; pB1 += 128;
    }
    PRD(0, 0); PSTG_A(1, 1, 1); PSTG_B(1, 1, 1);
    PFENCE; VMC(8); BAR;
    PRD(0, 1);
    PFENCE; VMC(4); BAR;
    PRD(1, 0);
    PFENCE; VMC(0); BAR;
    PRD(1, 1);
    PFENCE;

    // ---- rowsum completion: quad reduce; all lanes get row m*16+l16 sum ---
#pragma unroll
    for (int m = 0; m < 4; ++m) {
        rs[m] += __shfl_xor(rs[m], 16);
        rs[m] += __shfl_xor(rs[m], 32);
    }

    // ---- epilogue: out = acc / rowsum[row]; rowsum for row quad*4+r lives
    // in lane l16 = quad*4+r ----
    float* ob = out + (long)bz * (2048L * 1024);
#pragma unroll
    for (int m = 0; m < 4; ++m)
#pragma unroll
        for (int r = 0; r < 4; ++r) {
            const int row = mBase + wrow * 64 + m * 16 + quad * 4 + r;
            const float inv = 1.f / __shfl(rs[m], quad * 4 + r);
#pragma unroll
            for (int n = 0; n < 4; ++n) {
                const int col = nBase + wcol * 64 + n * 16 + l16;
                ob[(long)row * 1024 + col] = acc[m][n][r] * inv;
            }
        }
}

#undef PSTG_A
#undef PSTG_B
#undef PRD
#undef PFENCE
#undef PSUM
#undef VMC
#undef BAR

// ============================================================================
// r13: merged input/weight conversion.
// Blocks [0, 8192): inp f32 -> f16 (8192x1024). Blocks [8192, 11264): the
// three 1024x1024 weights -> contiguous f16 [3072][1024].
// ============================================================================
__global__ void cvt_all(const float* __restrict__ inp,
                        const float* __restrict__ W0,
                        const float* __restrict__ W1,
                        const float* __restrict__ W2,
                        f16* __restrict__ inp16, f16* __restrict__ W3)
{
    const int bxx = blockIdx.x;
    const float* src;
    f16* dst;
    int i;
    if (bxx < 8192) {
        src = inp; dst = inp16;
        i = bxx * 256 + threadIdx.x;
    } else {
        const int wb = bxx - 8192;          // 0..3071
        const int which = wb >> 10;
        src = (which == 0) ? W0 : (which == 1) ? W1 : W2;
        dst = W3 + (long)which * 1024 * 1024;
        i = (wb & 1023) * 256 + threadIdx.x;
    }
    const float4 v = ((const float4*)src)[i];
    f16x4v o;
    o[0] = (f16)v.x; o[1] = (f16)v.y; o[2] = (f16)v.z; o[3] = (f16)v.w;
    ((f16x4v*)dst)[i] = o;
}

extern "C" void kernel_launch(void* const* d_in, const int* in_sizes, int n_in,
                              void* d_out, int out_size, void* d_ws, size_t ws_size,
                              hipStream_t stream)
{
    const float* inp = (const float*)d_in[0];
    const int* masked = (const int*)d_in[1];
    const float* Wq = (const float*)d_in[2];
    const float* bq = (const float*)d_in[3];
    const float* Wk = (const float*)d_in[4];
    const float* bk = (const float*)d_in[5];
    const float* Wv = (const float*)d_in[6];
    const float* bv = (const float*)d_in[7];
    float* out = (float*)d_out;

    const int S = 2048, E = 1024;
    const long nTok = (long)4 * S;    // 8192

    // workspace (~102 MB). W3 segments must stay contiguous (one Bt operand).
    char* ws = (char*)d_ws;
    f16* inp16 = (f16*)ws;   ws += nTok * E * 2;         // 16 MB
    f16* W3    = (f16*)ws;   ws += (long)3 * E * E * 2;  //  6 MB
    f16* Q16   = (f16*)ws;   ws += nTok * E * 2;         // 16 MB
    f16* K16   = (f16*)ws;   ws += nTok * E * 2;         // 16 MB
    f16* Vt16  = (f16*)ws;   ws += nTok * E * 2;         // 16 MB ([b][e][s])
    f16* P16   = (f16*)ws;   ws += (long)4 * S * S * 2;  // 32 MB

    // f32 -> f16 conversions (one dispatch)
    cvt_all<<<dim3(8192 + 3072), dim3(256), 0, stream>>>(
        inp, Wq, Wk, Wv, inp16, W3);

    // fused QKV: 128x256-tile, 768 blocks, 4 waves of 128x64 (r21),
    // 3-buffer 1-step-per-phase, L2-resident XCD order (r16)
    qkv128<<<dim3(768), dim3(256), 0, stream>>>(
        inp16, W3, bq, bk, bv, Q16, K16, Vt16);

    // P = exp(QK^T/32): 128x128-tile 4-phase, 2 blocks/CU (r16)
    scores128<<<dim3(16, 16, 4), dim3(256), 0, stream>>>(
        Q16, K16, P16, masked);

    // out = (P @ V)/rowsum: 128x128-tile 4-phase, balanced pairing,
    // 128-granular causal K-limit, grid (8,16,4) (r17)
    pv128<<<dim3(8, 16, 4), dim3(256), 0, stream>>>(
        P16, Vt16, out, masked);
}